// Round 17
// baseline (1906.137 us; speedup 1.0000x reference)
//
#include <hip/hip_runtime.h>
#include <math.h>

// LSTM anomaly scan, B=256 T=1024 I=8 H=164 O=1, WL=0, THRESH=0.1.
// One block (704 thr = 11 waves) per batch element, sequential t-loop.
//
// r16 bench was an infra failure (container died twice) — this is the
// SAME kernel resubmitted. Design rationale (r15 post-mortem): ledger
// closes on DS pipe (step 3730cy ~= 121 plane reads x ~12cy + 451
// uniform h reads x ~5cy = 3707cy), but r15's 4-chain win proved pkfma
// chain latency still partially exposed. r16 = SIX accumulator chains
// at ZERO new registers — x-part scalars (xp0..3) repack as f2 chains
// (x01,x23) absorbing 1/3 of matvec quads, round-robin E/O/X:
// depth 21 -> 14. If flat: DS-pipe roofline confirmed.
// Everything else identical to r15/r11: 20 pinned / 10 streamed /
// 11 LDS planes, planes-first order, lgkm-only barrier, gate-
// interleaved rows (4 DPP quad_perm + ONE c/h chain epilogue),
// double-buffered shared h, uniform-address h-quad reads, pk_fma,
// branchless activation, DPP wave-sum pred, rcp+Newton math.

typedef __attribute__((ext_vector_type(4))) float f4;
typedef __attribute__((ext_vector_type(2))) float f2;

namespace {
constexpr int kB = 256;
constexpr int kT = 1024;
constexpr int kI = 8;
constexpr int kH = 164;
constexpr int kG = 4 * kH;                     // 656
constexpr int kThreads = 704;                  // 11 waves
constexpr int kRegQ = 20;                      // pinned quads (cols 0..79)
constexpr int kStrBase = kRegQ * 4;            // 80
constexpr int kStrC = 10;                      // streamed quads (cols 80..119)
constexpr int kLdsBase = kStrBase + kStrC * 4; // 120
constexpr int kLdsC = (kH - kLdsBase) / 4;     // 11 planes (cols 120..163)
constexpr int kQ = kH / 4;                     // 41 h-quads
constexpr int kQP = 44;                        // padded h buffer (f4 units)
constexpr float kThresh = 0.1f;

__device__ __forceinline__ float rlane(float v, int l) {
    return __int_as_float(__builtin_amdgcn_readlane(__float_as_int(v), l));
}
template <int CTRL>
__device__ __forceinline__ float dpp_mov(float x) {
    int t = __builtin_amdgcn_update_dpp(0, __float_as_int(x), CTRL, 0xf, 0xf, true);
    return __int_as_float(t);
}
// full-wave sum, result broadcast via lane 63
__device__ __forceinline__ float wave_sum(float x) {
    x += dpp_mov<0x111>(x);   // row_shr:1
    x += dpp_mov<0x112>(x);   // row_shr:2
    x += dpp_mov<0x114>(x);   // row_shr:4
    x += dpp_mov<0x118>(x);   // row_shr:8
    x += dpp_mov<0x142>(x);   // row_bcast:15
    x += dpp_mov<0x143>(x);   // row_bcast:31
    return rlane(x, 63);
}
// packed fp32 FMA: a.lo += w.lo*h.lo; a.hi += w.hi*h.hi  (VOP3P)
__device__ __forceinline__ void pkfma(f2& a, f2 w, f2 h) {
    asm("v_pk_fma_f32 %0, %1, %2, %0" : "+v"(a) : "v"(w), "v"(h));
}
// pair extraction helpers (macro-argument-safe: no braces at call sites)
__device__ __forceinline__ f2 lo2(f4 v) { f2 r; r.x = v.x; r.y = v.y; return r; }
__device__ __forceinline__ f2 hi2(f4 v) { f2 r; r.x = v.z; r.y = v.w; return r; }
// rcp + one Newton iteration: ~0.5 ulp at 3 instructions
__device__ __forceinline__ float fast_rcp(float d) {
    float r = __builtin_amdgcn_rcpf(d);
    float e = fmaf(-d, r, 1.0f);
    return fmaf(r, e, r);
}
// sigma(x), overflow-safe (clamp inf exp before Newton step)
__device__ __forceinline__ float sigm_c(float x) {
    float e = fminf(__expf(-x), 3.0e38f);
    return fast_rcp(1.0f + e);
}
// tanh(x) = 2*sigma(2x) - 1
__device__ __forceinline__ float tanh_c(float x) {
    return fmaf(2.0f, sigm_c(2.0f * x), -1.0f);
}
// lgkmcnt-only barrier: h ds_writes must be visible (LDS), but global
// stores/loads may stay in flight (no vmcnt drain).
__device__ __forceinline__ void barrier_lds_only() {
    asm volatile("s_waitcnt lgkmcnt(0)" ::: "memory");
    __builtin_amdgcn_s_barrier();
    __builtin_amdgcn_sched_barrier(0);
}
} // namespace

__global__
__attribute__((amdgpu_flat_work_group_size(kThreads, kThreads)))
__attribute__((amdgpu_waves_per_eu(3, 3)))
void lstm_anom_kernel(
    const float* __restrict__ x,     // (B,T,I)
    const float* __restrict__ Wih,   // (4H,I)
    const float* __restrict__ Whh,   // (4H,H)
    const float* __restrict__ bih,   // (4H)
    const float* __restrict__ bhh,   // (4H)
    const float* __restrict__ Wout,  // (1,H)
    const float* __restrict__ bout,  // (1)
    float* __restrict__ out)         // preds (B,T) then flags (B,T)
{
    __shared__ f4 wp[kLdsC * kG];    // 11*656*16 = 115456 B
    __shared__ f4 hL[2 * kQP];       // 1408 B  (total 116864 B)

    const int tid  = threadIdx.x;
    const int lane = tid & 63;
    const int b    = blockIdx.x;
    const int slot = (tid < kG) ? tid : (kG - 1);
    const int row  = (slot & 3) * kH + (slot >> 2);  // gate-interleaved
    const bool is_tanh = ((slot & 3) == 2);
    // branchless activation constants: av = m*sigma(m*acc) + (1-m)
    const float am = is_tanh ? 2.0f : 1.0f;
    const float ao = 1.0f - am;

    // ---- stage W_hh tail planes (cols 120..163), slot-indexed ----
    for (int i = tid; i < kLdsC * kG; i += kThreads) {
        const int c = i / kG, s = i - c * kG;
        const int rr = (s & 3) * kH + (s >> 2);
        wp[i] = *(const f4*)(Whh + (size_t)rr * kH + kLdsBase + 4 * c);
    }
    for (int i = tid; i < 2 * kQP; i += kThreads)
        hL[i] = (f4){0.f, 0.f, 0.f, 0.f};

    // ---- pinned weights: cols 0..79 as 40 f2 pairs + W_ih (2 f4) ----
    const f2* wr2 = (const f2*)(Whh + (size_t)row * kH);
    f2 p00 = wr2[0],  p01 = wr2[1],  p02 = wr2[2],  p03 = wr2[3];
    f2 p04 = wr2[4],  p05 = wr2[5],  p06 = wr2[6],  p07 = wr2[7];
    f2 p08 = wr2[8],  p09 = wr2[9],  p10 = wr2[10], p11 = wr2[11];
    f2 p12 = wr2[12], p13 = wr2[13], p14 = wr2[14], p15 = wr2[15];
    f2 p16 = wr2[16], p17 = wr2[17], p18 = wr2[18], p19 = wr2[19];
    f2 p20 = wr2[20], p21 = wr2[21], p22 = wr2[22], p23 = wr2[23];
    f2 p24 = wr2[24], p25 = wr2[25], p26 = wr2[26], p27 = wr2[27];
    f2 p28 = wr2[28], p29 = wr2[29], p30 = wr2[30], p31 = wr2[31];
    f2 p32 = wr2[32], p33 = wr2[33], p34 = wr2[34], p35 = wr2[35];
    f2 p36 = wr2[36], p37 = wr2[37], p38 = wr2[38], p39 = wr2[39];
    asm volatile("" : "+v"(p00), "+v"(p01), "+v"(p02), "+v"(p03),
                      "+v"(p04), "+v"(p05), "+v"(p06), "+v"(p07),
                      "+v"(p08), "+v"(p09), "+v"(p10), "+v"(p11),
                      "+v"(p12), "+v"(p13), "+v"(p14), "+v"(p15));
    asm volatile("" : "+v"(p16), "+v"(p17), "+v"(p18), "+v"(p19),
                      "+v"(p20), "+v"(p21), "+v"(p22), "+v"(p23),
                      "+v"(p24), "+v"(p25), "+v"(p26), "+v"(p27),
                      "+v"(p28), "+v"(p29), "+v"(p30), "+v"(p31));
    asm volatile("" : "+v"(p32), "+v"(p33), "+v"(p34), "+v"(p35),
                      "+v"(p36), "+v"(p37), "+v"(p38), "+v"(p39));
    f4 wih0 = ((const f4*)(Wih + (size_t)row * kI))[0];
    f4 wih1 = ((const f4*)(Wih + (size_t)row * kI))[1];
    asm volatile("" : "+v"(wih0), "+v"(wih1));
    float bsum = bih[row] + bhh[row];
    const int u2 = (lane < kH - 128) ? (128 + lane) : (kH - 1); // clamp
    float wo0 = Wout[lane];
    float wo1 = Wout[64 + lane];
    float wo2 = (128 + lane < kH) ? Wout[128 + lane] : 0.0f;    // kills dup
    asm volatile("" : "+v"(bsum), "+v"(wo0), "+v"(wo1), "+v"(wo2));
    const float bo = bout[0];

    // streamed cols 80..119: 10 loads, all base + immediate offset
    const f4* ws = (const f4*)(Whh + (size_t)row * kH + kStrBase);

    // per-lane persistent cell state for this thread's unit (quad-redundant)
    float vc = 0.f;
    float pred = 0.f;

    const float* xb = x + (size_t)b * kT * kI;
    float* pred_out = out + (size_t)b * kT;
    float* flag_out = out + (size_t)kB * kT + (size_t)b * kT;

    // 3 LDS base pointers keep tail ds_read offsets within imm range
    const f4* wt0 = wp + slot;            // planes 0..4
    const f4* wt5 = wp + 5 * kG + slot;   // planes 5..9
    const f4* wtA = wp + 10 * kG + slot;  // plane 10

    f4 xa = ((const f4*)xb)[0];
    f4 xc = ((const f4*)xb)[1];

    __syncthreads();

    // quad Q -> chain E / O / X (round-robin): depth 41 -> ~14 per chain
    #define GRPE(WLO, WHI, Q) { \
        const f4 hq = hc[Q]; \
        pkfma(a01e, (WLO), lo2(hq)); \
        pkfma(a23e, (WHI), hi2(hq)); }
    #define GRPO(WLO, WHI, Q) { \
        const f4 hq = hc[Q]; \
        pkfma(a01o, (WLO), lo2(hq)); \
        pkfma(a23o, (WHI), hi2(hq)); }
    #define GRPX(WLO, WHI, Q) { \
        const f4 hq = hc[Q]; \
        pkfma(x01, (WLO), lo2(hq)); \
        pkfma(x23, (WHI), hi2(hq)); }

    for (int t = 0; t < kT; ++t) {
        const f4*  hc = hL + (t & 1) * kQP;                 // read buffer
        float*     hn = (float*)(hL + ((t + 1) & 1) * kQP); // write buffer

        // ---- stream batch A issue (cols 80..99) ----
        f4 sA0 = ws[0], sA1 = ws[1], sA2 = ws[2], sA3 = ws[3], sA4 = ws[4];

        const bool  anom = (t > 0) && (fabsf(pred - xa.x) > kThresh);
        const float x0e  = anom ? pred : xa.x;

        // ---- x-part: 4 scalar chains, then repacked into f2 X-chains ----
        float xp0 = fmaf(x0e, wih0.x, bsum);
        float xp1 = xa.y * wih0.y;
        float xp2 = xa.z * wih0.z;
        float xp3 = xa.w * wih0.w;
        xp0 = fmaf(xc.x, wih1.x, xp0);
        xp1 = fmaf(xc.y, wih1.y, xp1);
        xp2 = fmaf(xc.z, wih1.z, xp2);
        xp3 = fmaf(xc.w, wih1.w, xp3);
        f2 x01; x01.x = xp0; x01.y = xp1;   // X chains reuse xp storage
        f2 x23; x23.x = xp2; x23.y = xp3;

        // ---- stream batch B issue (cols 100..119) ----
        f4 sB0 = ws[5], sB1 = ws[6], sB2 = ws[7], sB3 = ws[8], sB4 = ws[9];

        // prefetch x[t+1] (uniform across block — single line)
        const f4* nx = (const f4*)(xb + (size_t)((t + 1 < kT) ? t + 1 : t) * kI);
        f4 na = nx[0];
        f4 nc = nx[1];

        f2 a01e = {0.f, 0.f};
        f2 a23e = {0.f, 0.f};
        f2 a01o = {0.f, 0.f};
        f2 a23o = {0.f, 0.f};

        // ---- LDS tail planes FIRST: quads 30..40 (cols 120..163) ----
        // round-robin index 0..10 -> E,O,X
        _Pragma("unroll")
        for (int c = 0; c < kLdsC; ++c) {
            const f4 w = (c < 5)  ? wt0[c * kG]
                       : (c < 10) ? wt5[(c - 5) * kG]
                                  : wtA[(c - 10) * kG];
            const f4 hq = hc[kLdsBase / 4 + c];
            if (c % 3 == 0) {
                pkfma(a01e, lo2(w), lo2(hq));
                pkfma(a23e, hi2(w), hi2(hq));
            } else if (c % 3 == 1) {
                pkfma(a01o, lo2(w), lo2(hq));
                pkfma(a23o, hi2(w), hi2(hq));
            } else {
                pkfma(x01, lo2(w), lo2(hq));
                pkfma(x23, hi2(w), hi2(hq));
            }
        }

        // ---- stream A,B: quads 20..29 — continue round-robin (11..20) ----
        GRPX(lo2(sA0), hi2(sA0), 20)  GRPE(lo2(sA1), hi2(sA1), 21)
        GRPO(lo2(sA2), hi2(sA2), 22)  GRPX(lo2(sA3), hi2(sA3), 23)
        GRPE(lo2(sA4), hi2(sA4), 24)  GRPO(lo2(sB0), hi2(sB0), 25)
        GRPX(lo2(sB1), hi2(sB1), 26)  GRPE(lo2(sB2), hi2(sB2), 27)
        GRPO(lo2(sB3), hi2(sB3), 28)  GRPX(lo2(sB4), hi2(sB4), 29)

        // ---- pinned quads LAST: 0..19 — continue round-robin (21..40) ----
        GRPE(p00, p01, 0)   GRPO(p02, p03, 1)   GRPX(p04, p05, 2)
        GRPE(p06, p07, 3)   GRPO(p08, p09, 4)   GRPX(p10, p11, 5)
        GRPE(p12, p13, 6)   GRPO(p14, p15, 7)   GRPX(p16, p17, 8)
        GRPE(p18, p19, 9)   GRPO(p20, p21, 10)  GRPX(p22, p23, 11)
        GRPE(p24, p25, 12)  GRPO(p26, p27, 13)  GRPX(p28, p29, 14)
        GRPE(p30, p31, 15)  GRPO(p32, p33, 16)  GRPX(p34, p35, 17)
        GRPE(p36, p37, 18)  GRPO(p38, p39, 19)

        // ---- merge 6 chains + branchless activation ----
        const f2 s01 = (a01e + a01o) + x01;
        const f2 s23 = (a23e + a23o) + x23;
        const float acc = (s01.x + s01.y) + (s23.x + s23.y);
        const float av  = fmaf(am, sigm_c(am * acc), ao);

        // ---- quad gather: unit u's 4 gates live in lanes 4u..4u+3 ----
        const float gi = dpp_mov<0x00>(av);   // quad_perm [0,0,0,0]
        const float gf = dpp_mov<0x55>(av);   // quad_perm [1,1,1,1]
        const float gg = dpp_mov<0xAA>(av);   // quad_perm [2,2,2,2]
        const float go = dpp_mov<0xFF>(av);   // quad_perm [3,3,3,3]

        // ---- c/h update: ONE chain per lane (quad-redundant) ----
        vc = fmaf(gf, vc, gi * gg);
        const float h = go * tanh_c(vc);

        // publish h (16 disjoint writes/wave) to NEXT buffer
        if (((tid & 3) == 0) && (tid < kG)) hn[tid >> 2] = h;

        // lgkmcnt-only barrier: global stores stay in flight
        barrier_lds_only();

        // ---- pred (redundant per wave): 3 per-lane h reads + DPP sum ----
        const float* hp = (const float*)(hL + ((t + 1) & 1) * kQP);
        const float h0 = hp[lane];
        const float h1 = hp[64 + lane];
        const float h2 = hp[u2];
        const float p  = fmaf(h0, wo0, fmaf(h1, wo1, h2 * wo2));
        pred = wave_sum(p) + bo;

        if (tid == 0) {
            pred_out[t] = pred;
            flag_out[t] = anom ? 1.0f : 0.0f;
        }
        xa = na;
        xc = nc;
    }
    #undef GRPX
    #undef GRPO
    #undef GRPE
}

extern "C" void kernel_launch(void* const* d_in, const int* in_sizes, int n_in,
                              void* d_out, int out_size, void* d_ws, size_t ws_size,
                              hipStream_t stream) {
    const float* x    = (const float*)d_in[0];
    const float* Wih  = (const float*)d_in[1];
    const float* Whh  = (const float*)d_in[2];
    const float* bih  = (const float*)d_in[3];
    const float* bhh  = (const float*)d_in[4];
    const float* Wout = (const float*)d_in[5];
    const float* bout = (const float*)d_in[6];
    lstm_anom_kernel<<<dim3(kB), dim3(kThreads), 0, stream>>>(
        x, Wih, Whh, bih, bhh, Wout, bout, (float*)d_out);
}

// Round 18
// 1585.279 us; speedup vs baseline: 1.2024x; 1.2024x over previous
//
#include <hip/hip_runtime.h>
#include <math.h>

// LSTM anomaly scan, B=256 T=1024 I=8 H=164 O=1, WL=0, THRESH=0.1.
// One block (704 thr = 11 waves) per batch element, sequential t-loop.
//
// r17 post-mortem: 6-chain round-robin SPILLED (WRITE_SIZE 2048->7680KB,
// 1906us) — all six accumulators live across all three sections at once.
// Chain axis closed: 4 chains optimal (2->4 won +64us, 4->6 spills).
// This is r15 RESTORED (1592us, verified best).
//
// Final structure: 20 pinned quads (cols 0..79, asm-pinned in unified
// VGPR/AGPR file) / 10 streamed quads (cols 80..119, issued at loop top,
// <=10 in flight) / 11 LDS weight planes (cols 120..163, slot-indexed,
// 0-conflict). Gate-interleaved row mapping (unit's 4 gates in one
// lane-quad; epilogue = 4 DPP quad_perm + ONE c/h chain, register-only).
// Double-buffered shared h; ONE lgkm-only barrier/step (global stores
// float across). Uniform-address h-quad broadcast reads. FOUR pkfma
// accumulator chains (even/odd quads) + separate x-part chains.
// Branchless activation via pre-scaled sigmoid; DPP wave-sum pred;
// rcp+Newton fast math (absmax 2.44e-4, unchanged since r0).
//
// DS-pipe ledger at 1592us (3730cy/step): 121 per-lane plane reads
// x ~12cy + 451 uniform h reads x ~5cy ~= 3707cy => LDS pipe ~99%
// occupied. h-broadcast redundancy (41 quads x 11 waves) is structural:
// every wave computes 64 distinct gate rows needing ALL 164 h values,
// and the thread mapping is forced by the closed register/stream budget.

typedef __attribute__((ext_vector_type(4))) float f4;
typedef __attribute__((ext_vector_type(2))) float f2;

namespace {
constexpr int kB = 256;
constexpr int kT = 1024;
constexpr int kI = 8;
constexpr int kH = 164;
constexpr int kG = 4 * kH;                     // 656
constexpr int kThreads = 704;                  // 11 waves
constexpr int kRegQ = 20;                      // pinned quads (cols 0..79)
constexpr int kStrBase = kRegQ * 4;            // 80
constexpr int kStrC = 10;                      // streamed quads (cols 80..119)
constexpr int kLdsBase = kStrBase + kStrC * 4; // 120
constexpr int kLdsC = (kH - kLdsBase) / 4;     // 11 planes (cols 120..163)
constexpr int kQ = kH / 4;                     // 41 h-quads
constexpr int kQP = 44;                        // padded h buffer (f4 units)
constexpr float kThresh = 0.1f;

__device__ __forceinline__ float rlane(float v, int l) {
    return __int_as_float(__builtin_amdgcn_readlane(__float_as_int(v), l));
}
template <int CTRL>
__device__ __forceinline__ float dpp_mov(float x) {
    int t = __builtin_amdgcn_update_dpp(0, __float_as_int(x), CTRL, 0xf, 0xf, true);
    return __int_as_float(t);
}
// full-wave sum, result broadcast via lane 63
__device__ __forceinline__ float wave_sum(float x) {
    x += dpp_mov<0x111>(x);   // row_shr:1
    x += dpp_mov<0x112>(x);   // row_shr:2
    x += dpp_mov<0x114>(x);   // row_shr:4
    x += dpp_mov<0x118>(x);   // row_shr:8
    x += dpp_mov<0x142>(x);   // row_bcast:15
    x += dpp_mov<0x143>(x);   // row_bcast:31
    return rlane(x, 63);
}
// packed fp32 FMA: a.lo += w.lo*h.lo; a.hi += w.hi*h.hi  (VOP3P)
__device__ __forceinline__ void pkfma(f2& a, f2 w, f2 h) {
    asm("v_pk_fma_f32 %0, %1, %2, %0" : "+v"(a) : "v"(w), "v"(h));
}
// pair extraction helpers (macro-argument-safe: no braces at call sites)
__device__ __forceinline__ f2 lo2(f4 v) { f2 r; r.x = v.x; r.y = v.y; return r; }
__device__ __forceinline__ f2 hi2(f4 v) { f2 r; r.x = v.z; r.y = v.w; return r; }
// rcp + one Newton iteration: ~0.5 ulp at 3 instructions
__device__ __forceinline__ float fast_rcp(float d) {
    float r = __builtin_amdgcn_rcpf(d);
    float e = fmaf(-d, r, 1.0f);
    return fmaf(r, e, r);
}
// sigma(x), overflow-safe (clamp inf exp before Newton step)
__device__ __forceinline__ float sigm_c(float x) {
    float e = fminf(__expf(-x), 3.0e38f);
    return fast_rcp(1.0f + e);
}
// tanh(x) = 2*sigma(2x) - 1
__device__ __forceinline__ float tanh_c(float x) {
    return fmaf(2.0f, sigm_c(2.0f * x), -1.0f);
}
// lgkmcnt-only barrier: h ds_writes must be visible (LDS), but global
// stores/loads may stay in flight (no vmcnt drain).
__device__ __forceinline__ void barrier_lds_only() {
    asm volatile("s_waitcnt lgkmcnt(0)" ::: "memory");
    __builtin_amdgcn_s_barrier();
    __builtin_amdgcn_sched_barrier(0);
}
} // namespace

__global__
__attribute__((amdgpu_flat_work_group_size(kThreads, kThreads)))
__attribute__((amdgpu_waves_per_eu(3, 3)))
void lstm_anom_kernel(
    const float* __restrict__ x,     // (B,T,I)
    const float* __restrict__ Wih,   // (4H,I)
    const float* __restrict__ Whh,   // (4H,H)
    const float* __restrict__ bih,   // (4H)
    const float* __restrict__ bhh,   // (4H)
    const float* __restrict__ Wout,  // (1,H)
    const float* __restrict__ bout,  // (1)
    float* __restrict__ out)         // preds (B,T) then flags (B,T)
{
    __shared__ f4 wp[kLdsC * kG];    // 11*656*16 = 115456 B
    __shared__ f4 hL[2 * kQP];       // 1408 B  (total 116864 B)

    const int tid  = threadIdx.x;
    const int lane = tid & 63;
    const int b    = blockIdx.x;
    const int slot = (tid < kG) ? tid : (kG - 1);
    const int row  = (slot & 3) * kH + (slot >> 2);  // gate-interleaved
    const bool is_tanh = ((slot & 3) == 2);
    // branchless activation constants: av = m*sigma(m*acc) + (1-m)
    const float am = is_tanh ? 2.0f : 1.0f;
    const float ao = 1.0f - am;

    // ---- stage W_hh tail planes (cols 120..163), slot-indexed ----
    for (int i = tid; i < kLdsC * kG; i += kThreads) {
        const int c = i / kG, s = i - c * kG;
        const int rr = (s & 3) * kH + (s >> 2);
        wp[i] = *(const f4*)(Whh + (size_t)rr * kH + kLdsBase + 4 * c);
    }
    for (int i = tid; i < 2 * kQP; i += kThreads)
        hL[i] = (f4){0.f, 0.f, 0.f, 0.f};

    // ---- pinned weights: cols 0..79 as 40 f2 pairs + W_ih (2 f4) ----
    const f2* wr2 = (const f2*)(Whh + (size_t)row * kH);
    f2 p00 = wr2[0],  p01 = wr2[1],  p02 = wr2[2],  p03 = wr2[3];
    f2 p04 = wr2[4],  p05 = wr2[5],  p06 = wr2[6],  p07 = wr2[7];
    f2 p08 = wr2[8],  p09 = wr2[9],  p10 = wr2[10], p11 = wr2[11];
    f2 p12 = wr2[12], p13 = wr2[13], p14 = wr2[14], p15 = wr2[15];
    f2 p16 = wr2[16], p17 = wr2[17], p18 = wr2[18], p19 = wr2[19];
    f2 p20 = wr2[20], p21 = wr2[21], p22 = wr2[22], p23 = wr2[23];
    f2 p24 = wr2[24], p25 = wr2[25], p26 = wr2[26], p27 = wr2[27];
    f2 p28 = wr2[28], p29 = wr2[29], p30 = wr2[30], p31 = wr2[31];
    f2 p32 = wr2[32], p33 = wr2[33], p34 = wr2[34], p35 = wr2[35];
    f2 p36 = wr2[36], p37 = wr2[37], p38 = wr2[38], p39 = wr2[39];
    asm volatile("" : "+v"(p00), "+v"(p01), "+v"(p02), "+v"(p03),
                      "+v"(p04), "+v"(p05), "+v"(p06), "+v"(p07),
                      "+v"(p08), "+v"(p09), "+v"(p10), "+v"(p11),
                      "+v"(p12), "+v"(p13), "+v"(p14), "+v"(p15));
    asm volatile("" : "+v"(p16), "+v"(p17), "+v"(p18), "+v"(p19),
                      "+v"(p20), "+v"(p21), "+v"(p22), "+v"(p23),
                      "+v"(p24), "+v"(p25), "+v"(p26), "+v"(p27),
                      "+v"(p28), "+v"(p29), "+v"(p30), "+v"(p31));
    asm volatile("" : "+v"(p32), "+v"(p33), "+v"(p34), "+v"(p35),
                      "+v"(p36), "+v"(p37), "+v"(p38), "+v"(p39));
    f4 wih0 = ((const f4*)(Wih + (size_t)row * kI))[0];
    f4 wih1 = ((const f4*)(Wih + (size_t)row * kI))[1];
    asm volatile("" : "+v"(wih0), "+v"(wih1));
    float bsum = bih[row] + bhh[row];
    const int u2 = (lane < kH - 128) ? (128 + lane) : (kH - 1); // clamp
    float wo0 = Wout[lane];
    float wo1 = Wout[64 + lane];
    float wo2 = (128 + lane < kH) ? Wout[128 + lane] : 0.0f;    // kills dup
    asm volatile("" : "+v"(bsum), "+v"(wo0), "+v"(wo1), "+v"(wo2));
    const float bo = bout[0];

    // streamed cols 80..119: 10 loads, all base + immediate offset
    const f4* ws = (const f4*)(Whh + (size_t)row * kH + kStrBase);

    // per-lane persistent cell state for this thread's unit (quad-redundant)
    float vc = 0.f;
    float pred = 0.f;

    const float* xb = x + (size_t)b * kT * kI;
    float* pred_out = out + (size_t)b * kT;
    float* flag_out = out + (size_t)kB * kT + (size_t)b * kT;

    // 3 LDS base pointers keep tail ds_read offsets within imm range
    const f4* wt0 = wp + slot;            // planes 0..4
    const f4* wt5 = wp + 5 * kG + slot;   // planes 5..9
    const f4* wtA = wp + 10 * kG + slot;  // plane 10

    f4 xa = ((const f4*)xb)[0];
    f4 xc = ((const f4*)xb)[1];

    __syncthreads();

    // quad Q -> chain E (even) or O (odd): halves the pkfma dep depth
    #define GRPQE(WLO, WHI, Q) { \
        const f4 hq = hc[Q]; \
        pkfma(a01e, (WLO), lo2(hq)); \
        pkfma(a23e, (WHI), hi2(hq)); }
    #define GRPQO(WLO, WHI, Q) { \
        const f4 hq = hc[Q]; \
        pkfma(a01o, (WLO), lo2(hq)); \
        pkfma(a23o, (WHI), hi2(hq)); }

    for (int t = 0; t < kT; ++t) {
        const f4*  hc = hL + (t & 1) * kQP;                 // read buffer
        float*     hn = (float*)(hL + ((t + 1) & 1) * kQP); // write buffer

        // ---- stream batch A issue (cols 80..99) ----
        f4 sA0 = ws[0], sA1 = ws[1], sA2 = ws[2], sA3 = ws[3], sA4 = ws[4];

        const bool  anom = (t > 0) && (fabsf(pred - xa.x) > kThresh);
        const float x0e  = anom ? pred : xa.x;

        // ---- x-part in separate chains (merged at activation) ----
        float xp0 = fmaf(x0e, wih0.x, bsum);
        float xp1 = xa.y * wih0.y;
        float xp2 = xa.z * wih0.z;
        float xp3 = xa.w * wih0.w;
        xp0 = fmaf(xc.x, wih1.x, xp0);
        xp1 = fmaf(xc.y, wih1.y, xp1);
        xp2 = fmaf(xc.z, wih1.z, xp2);
        xp3 = fmaf(xc.w, wih1.w, xp3);

        // ---- stream batch B issue (cols 100..119) ----
        f4 sB0 = ws[5], sB1 = ws[6], sB2 = ws[7], sB3 = ws[8], sB4 = ws[9];

        // prefetch x[t+1] (uniform across block — single line)
        const f4* nx = (const f4*)(xb + (size_t)((t + 1 < kT) ? t + 1 : t) * kI);
        f4 na = nx[0];
        f4 nc = nx[1];

        f2 a01e = {0.f, 0.f};
        f2 a23e = {0.f, 0.f};
        f2 a01o = {0.f, 0.f};
        f2 a23o = {0.f, 0.f};

        // ---- LDS tail planes FIRST: quads 30..40 (cols 120..163) ----
        _Pragma("unroll")
        for (int c = 0; c < kLdsC; ++c) {
            const f4 w = (c < 5)  ? wt0[c * kG]
                       : (c < 10) ? wt5[(c - 5) * kG]
                                  : wtA[(c - 10) * kG];
            const f4 hq = hc[kLdsBase / 4 + c];
            if (c & 1) {
                pkfma(a01o, lo2(w), lo2(hq));
                pkfma(a23o, hi2(w), hi2(hq));
            } else {
                pkfma(a01e, lo2(w), lo2(hq));
                pkfma(a23e, hi2(w), hi2(hq));
            }
        }

        // ---- stream A,B: quads 20..29 (cols 80..119), alternating ----
        GRPQE(lo2(sA0), hi2(sA0), 20)  GRPQO(lo2(sA1), hi2(sA1), 21)
        GRPQE(lo2(sA2), hi2(sA2), 22)  GRPQO(lo2(sA3), hi2(sA3), 23)
        GRPQE(lo2(sA4), hi2(sA4), 24)  GRPQO(lo2(sB0), hi2(sB0), 25)
        GRPQE(lo2(sB1), hi2(sB1), 26)  GRPQO(lo2(sB2), hi2(sB2), 27)
        GRPQE(lo2(sB3), hi2(sB3), 28)  GRPQO(lo2(sB4), hi2(sB4), 29)

        // ---- pinned quads LAST: 0..19 (cols 0..79), alternating ----
        GRPQE(p00, p01, 0)   GRPQO(p02, p03, 1)
        GRPQE(p04, p05, 2)   GRPQO(p06, p07, 3)
        GRPQE(p08, p09, 4)   GRPQO(p10, p11, 5)
        GRPQE(p12, p13, 6)   GRPQO(p14, p15, 7)
        GRPQE(p16, p17, 8)   GRPQO(p18, p19, 9)
        GRPQE(p20, p21, 10)  GRPQO(p22, p23, 11)
        GRPQE(p24, p25, 12)  GRPQO(p26, p27, 13)
        GRPQE(p28, p29, 14)  GRPQO(p30, p31, 15)
        GRPQE(p32, p33, 16)  GRPQO(p34, p35, 17)
        GRPQE(p36, p37, 18)  GRPQO(p38, p39, 19)

        // ---- branchless activation: av = m*sigma(m*acc) + (1-m) ----
        const f2 a01 = a01e + a01o;
        const f2 a23 = a23e + a23o;
        const float acc = ((a01.x + a01.y) + (a23.x + a23.y))
                        + ((xp0 + xp1) + (xp2 + xp3));
        const float av  = fmaf(am, sigm_c(am * acc), ao);

        // ---- quad gather: unit u's 4 gates live in lanes 4u..4u+3 ----
        const float gi = dpp_mov<0x00>(av);   // quad_perm [0,0,0,0]
        const float gf = dpp_mov<0x55>(av);   // quad_perm [1,1,1,1]
        const float gg = dpp_mov<0xAA>(av);   // quad_perm [2,2,2,2]
        const float go = dpp_mov<0xFF>(av);   // quad_perm [3,3,3,3]

        // ---- c/h update: ONE chain per lane (quad-redundant) ----
        vc = fmaf(gf, vc, gi * gg);
        const float h = go * tanh_c(vc);

        // publish h (16 disjoint writes/wave) to NEXT buffer
        if (((tid & 3) == 0) && (tid < kG)) hn[tid >> 2] = h;

        // lgkmcnt-only barrier: global stores stay in flight
        barrier_lds_only();

        // ---- pred (redundant per wave): 3 per-lane h reads + DPP sum ----
        const float* hp = (const float*)(hL + ((t + 1) & 1) * kQP);
        const float h0 = hp[lane];
        const float h1 = hp[64 + lane];
        const float h2 = hp[u2];
        const float p  = fmaf(h0, wo0, fmaf(h1, wo1, h2 * wo2));
        pred = wave_sum(p) + bo;

        if (tid == 0) {
            pred_out[t] = pred;
            flag_out[t] = anom ? 1.0f : 0.0f;
        }
        xa = na;
        xc = nc;
    }
    #undef GRPQO
    #undef GRPQE
}

extern "C" void kernel_launch(void* const* d_in, const int* in_sizes, int n_in,
                              void* d_out, int out_size, void* d_ws, size_t ws_size,
                              hipStream_t stream) {
    const float* x    = (const float*)d_in[0];
    const float* Wih  = (const float*)d_in[1];
    const float* Whh  = (const float*)d_in[2];
    const float* bih  = (const float*)d_in[3];
    const float* bhh  = (const float*)d_in[4];
    const float* Wout = (const float*)d_in[5];
    const float* bout = (const float*)d_in[6];
    lstm_anom_kernel<<<dim3(kB), dim3(kThreads), 0, stream>>>(
        x, Wih, Whh, bih, bhh, Wout, bout, (float*)d_out);
}